// Round 7
// baseline (171.249 us; speedup 1.0000x reference)
//
#include <hip/hip_runtime.h>

// B=16, C=1, H=512, W=640
#define BB 16
#define HH 512
#define WW 640
constexpr int HW = HH * WW;

#define WT 64
#define HT 16
#define RP 4                 // center rows per thread
#define PAD 4
#define LW (WT + 2*PAD)      // 72 (left+right halo)
#define LH (HT + PAD)        // 20 (bottom halo only; pair symmetry needs no top)
#define GX (WW / WT)         // 10
#define GY (HH / HT)         // 32
#define NBLK (GX * GY * BB)  // 5120

constexpr float HALO = 1.0e6f;   // OOB fill: both signs +1 -> c=0

__device__ __forceinline__ float fast_rcp(float x) {
    return __builtin_amdgcn_rcpf(x);
}

// ---- interior core: XOR-census, all pair weights 2/81 (applied by caller)
__device__ __forceinline__ float census_interior(const float* es_t, const float* ta_t,
                                                 int tx, int rg)
{
    float ehi[RP], elo[RP], thi[RP], tlo[RP];
    #pragma unroll
    for (int p = 0; p < RP; ++p) {
        int lr = rg * RP + p;
        float ec = es_t[lr * LW + tx + PAD];
        float tc = ta_t[lr * LW + tx + PAD];
        ehi[p] = ec + 0.5f;  elo[p] = ec - 0.5f;
        thi[p] = tc + 0.5f;  tlo[p] = tc - 0.5f;
    }

    int acca[RP] = {0, 0, 0, 0};   // hi-threshold xor bits, per-center chains
    int accb[RP] = {0, 0, 0, 0};   // lo-threshold xor bits

    #pragma unroll
    for (int wr = 0; wr < RP + PAD; ++wr) {     // 8 window rows
        const int lr = rg * RP + wr;
        float e[9], t[9];
        #pragma unroll
        for (int j = 0; j < 9; ++j) {
            e[j] = es_t[lr * LW + tx + j];
            t[j] = ta_t[lr * LW + tx + j];
        }
        if (wr < RP) {                          // dh == 0, forward cols only
            #pragma unroll
            for (int j = 5; j <= 8; ++j) {
                acca[wr] += (int)((e[j] > ehi[wr]) != (t[j] > thi[wr]));
                accb[wr] += (int)((e[j] < elo[wr]) != (t[j] < tlo[wr]));
            }
        }
        #pragma unroll
        for (int p = 0; p < RP; ++p) {          // dh = wr-p in 1..4
            if (p <= wr - 1 && p >= wr - PAD) {
                #pragma unroll
                for (int j = 0; j <= 8; ++j) {
                    acca[p] += (int)((e[j] > ehi[p]) != (t[j] > thi[p]));
                    accb[p] += (int)((e[j] < elo[p]) != (t[j] < tlo[p]));
                }
            }
        }
    }
    int acc = (acca[0] + acca[1]) + (acca[2] + acca[3])
            + (accb[0] + accb[1]) + (accb[2] + accb[3]);
    return (float)acc;
}

// ---- edge core: same window structure, exact f32 signs, per-pair weights
__device__ __forceinline__ float census_edge(const float* es_t, const float* ta_t,
                                             int tx, int rg, int bx, int by)
{
    float invcw[9];
    const int w0 = bx * WT + tx;
    #pragma unroll
    for (int j = 0; j < 9; ++j) {
        int c  = w0 + j - PAD;                  // may be OOB: cw>=1 there, c==0
        int cw = min(PAD, WW - 1 - c) + min(PAD, c) + 1;
        invcw[j] = fast_rcp((float)cw);
    }
    float rowinv[RP + PAD];
    #pragma unroll
    for (int wr = 0; wr < RP + PAD; ++wr) {
        int r  = by * HT + rg * RP + wr;        // may be OOB: ch>=1
        int ch = min(PAD, HH - 1 - r) + min(PAD, r) + 1;
        rowinv[wr] = fast_rcp((float)ch);
    }

    float ec[RP], tc[RP], wp[RP], facc[RP];
    #pragma unroll
    for (int p = 0; p < RP; ++p) {
        int lr = rg * RP + p;
        ec[p] = es_t[lr * LW + tx + PAD];
        tc[p] = ta_t[lr * LW + tx + PAD];
        wp[p] = rowinv[p] * invcw[PAD];         // center's 1/count
        facc[p] = 0.0f;
    }

    #pragma unroll
    for (int wr = 0; wr < RP + PAD; ++wr) {
        const int lr = rg * RP + wr;
        float e[9], t[9];
        #pragma unroll
        for (int j = 0; j < 9; ++j) {
            e[j] = es_t[lr * LW + tx + j];
            t[j] = ta_t[lr * LW + tx + j];
        }
        #pragma unroll
        for (int p = 0; p < RP; ++p) {
            const bool d0 = (p == wr);
            if (p <= wr && p >= wr - PAD) {
                #pragma unroll
                for (int j = 0; j <= 8; ++j) {
                    if (d0 && j <= 4) continue;   // dh==0: forward cols only
                    float s1 = rintf(__builtin_amdgcn_fmed3f(e[j] - ec[p], -1.0f, 1.0f));
                    float s2 = rintf(__builtin_amdgcn_fmed3f(t[j] - tc[p], -1.0f, 1.0f));
                    float c  = fabsf(s1 - s2);
                    float wt = fmaf(rowinv[wr], invcw[j], wp[p]);  // 1/cnt_q + 1/cnt_p
                    facc[p] = fmaf(c, wt, facc[p]);
                }
            }
        }
    }
    return (facc[0] + facc[1]) + (facc[2] + facc[3]);
}

__global__ __launch_bounds__(256)
void fused_kernel(const float* __restrict__ disp0,
                  const float* __restrict__ im,
                  const float* __restrict__ pattern,
                  float* __restrict__ out,       // [val, proj...]
                  float* __restrict__ partial)   // d_ws, NBLK floats
{
    __shared__ float es_t[LH * LW];
    __shared__ float ta_t[LH * LW];
    __shared__ float wsum[4];

    const int bx = blockIdx.x, by = blockIdx.y, b = blockIdx.z;
    const int tx = threadIdx.x;      // 0..63
    const int rg = threadIdx.y;      // 0..3
    const int tid = rg * 64 + tx;

    const float* db = disp0 + (size_t)b * HW;
    const float* ib = im    + (size_t)b * HW;
    float* proj = out + 1 + (size_t)b * HW;

    const int gh0 = by * HT;           // LDS row 0 == tile top (no top halo)
    const int gw0 = bx * WT - PAD;     // LDS col 0

    // ---- staging: fused projection + im (f32), proj written once per pixel
    #pragma unroll
    for (int it = 0; it < (LH * LW + 255) / 256; ++it) {
        int i = tid + it * 256;
        if (i < LH * LW) {
            int lh = i / LW;
            int lw = i - lh * LW;
            int gh = gh0 + lh, gw = gw0 + lw;
            float ev = HALO, tv = HALO;
            if ((gh < HH) & (gw >= 0) & (gw < WW)) {
                int g = gh * WW + gw;
                float d = db[g];
                float x = fminf(fmaxf((float)gw - d, 0.0f), (float)(WW - 1));
                int   x0 = (int)x;
                int   x1 = min(x0 + 1, WW - 1);
                float w  = x - (float)x0;
                const float* prow = pattern + gh * WW;
                float p0 = (prow[x0] + prow[HW + x0] + prow[2*HW + x0]) * (1.0f/3.0f);
                float p1 = (prow[x1] + prow[HW + x1] + prow[2*HW + x1]) * (1.0f/3.0f);
                ev = p0 * (1.0f - w) + p1 * w;
                tv = ib[g];
                if ((lh < HT) & (lw >= PAD) & (lw < PAD + WT))
                    proj[g] = ev;
            }
            es_t[i] = ev;
            ta_t[i] = tv;
        }
    }
    __syncthreads();

    // ---- census
    float tsum;
    if ((bx >= 1) & (bx <= GX - 2) & (by >= 1) & (by <= GY - 2)) {
        tsum = census_interior(es_t, ta_t, tx, rg) * (2.0f / 81.0f);
    } else {
        tsum = census_edge(es_t, ta_t, tx, rg, bx, by);
    }

    // ---- block reduce -> one partial per block
    #pragma unroll
    for (int off = 32; off > 0; off >>= 1)
        tsum += __shfl_down(tsum, off, 64);
    if (tx == 0) wsum[rg] = tsum;
    __syncthreads();
    if (tid == 0)
        partial[(b * GY + by) * GX + bx] = wsum[0] + wsum[1] + wsum[2] + wsum[3];
}

__global__ __launch_bounds__(256)
void reduce_kernel(const float* __restrict__ partial, float* __restrict__ out)
{
    __shared__ float wsum[4];
    int t = threadIdx.x;
    float s = 0.0f;
    #pragma unroll
    for (int i = 0; i < NBLK / 256; ++i) s += partial[t + i * 256];
    #pragma unroll
    for (int off = 32; off > 0; off >>= 1)
        s += __shfl_down(s, off, 64);
    if ((t & 63) == 0) wsum[t >> 6] = s;
    __syncthreads();
    if (t == 0)
        out[0] = (wsum[0] + wsum[1] + wsum[2] + wsum[3]) * (1.0f / ((float)BB * (float)HW));
}

extern "C" void kernel_launch(void* const* d_in, const int* in_sizes, int n_in,
                              void* d_out, int out_size, void* d_ws, size_t ws_size,
                              hipStream_t stream) {
    const float* disp0   = (const float*)d_in[0];
    const float* im      = (const float*)d_in[1];
    const float* pattern = (const float*)d_in[2];
    float* out = (float*)d_out;
    float* partial = (float*)d_ws;   // NBLK floats = 20 KB

    dim3 grid(GX, GY, BB);           // 10, 32, 16
    dim3 block(64, 4);
    fused_kernel<<<grid, block, 0, stream>>>(disp0, im, pattern, out, partial);
    reduce_kernel<<<1, 256, 0, stream>>>(partial, out);
}